// Round 17
// baseline (137.173 us; speedup 1.0000x reference)
//
#include <hip/hip_runtime.h>
#include <hip/hip_bf16.h>
#include <stddef.h>

#define B_SZ   32
#define N_SZ   512
#define M_SZ   512
#define D_SZ   256
#define HSLAB  128           // slabs per half: s = (i>>3)+(j>>2), 0..126 (+1 pad)
#define SLAB_U4 256          // 2048 bf16 per slab = 256 uint4
#define HALF_E (HSLAB * 2048)  // elements per half
#define BIGF   1e10f

#define NGEMM  512           // 16 tiles x 32 batches
#define NDTW   64            // 2 halves x 32 batches

typedef __attribute__((ext_vector_type(8))) short short8;
typedef __attribute__((ext_vector_type(4))) float f32x4;

__device__ __forceinline__ unsigned pack_bf16(float lo, float hi) {
    unsigned short a = __builtin_bit_cast(unsigned short, __float2bfloat16(lo));
    unsigned short b = __builtin_bit_cast(unsigned short, __float2bfloat16(hi));
    return (unsigned)a | ((unsigned)b << 16);
}

// ---------------------------------------------------------------------------
// Fused pre-pass (unchanged from R15 — proven).
// Blocks 0..16383: teacher row -> ybf (mean-of-4, bf16) + y2 norm.
// Blocks 16384..20479: x rows -> xbf (bf16 copy) + x2 norms (4 rows/block).
__global__ void __launch_bounds__(256) pre_kernel(const float* __restrict__ t,
                                                  const float* __restrict__ x,
                                                  ushort* __restrict__ ybf,
                                                  ushort* __restrict__ xbf,
                                                  float* __restrict__ y2,
                                                  float* __restrict__ x2) {
    if (blockIdx.x < 16384) {
        const int row = blockIdx.x;
        const int c   = threadIdx.x;
        float4 v = *((const float4*)t + (size_t)row * 256 + c);
        float m = (v.x + v.y + v.z + v.w) * 0.25f;
        ybf[(size_t)row * 256 + c] = __builtin_bit_cast(unsigned short, __float2bfloat16(m));
        float s = m * m;
        #pragma unroll
        for (int o = 32; o > 0; o >>= 1) s += __shfl_down(s, o);
        __shared__ float acc4[4];
        if ((c & 63) == 0) acc4[c >> 6] = s;
        __syncthreads();
        if (c == 0) y2[row] = (acc4[0] + acc4[1]) + (acc4[2] + acc4[3]);
    } else {
        const int wave = threadIdx.x >> 6;
        const int lane = threadIdx.x & 63;
        const int row  = (blockIdx.x - 16384) * 4 + wave;
        const float4* r4 = (const float4*)(x + (size_t)row * D_SZ);
        float4 v = r4[lane];
        *(uint2*)(xbf + (size_t)row * D_SZ + lane * 4) =
            make_uint2(pack_bf16(v.x, v.y), pack_bf16(v.z, v.w));
        float s = v.x*v.x + v.y*v.y + v.z*v.z + v.w*v.w;
        #pragma unroll
        for (int o = 32; o > 0; o >>= 1) s += __shfl_down(s, o);
        if (lane == 0) x2[row] = s;
    }
}

// ---------------------------------------------------------------------------
// DTW step (unchanged from R15): min3 form, 4-col chunks, anti-diagonal SSA,
// 4-deep slab prefetch.
template <bool HEAD>
__device__ __forceinline__ void dtw_step(int s, int lane,
    const uint4* __restrict__ base, uint4 (&q)[4],
    float (&V)[8], float (&top)[4], float& diag0)
{
    float d[4][8];
    #pragma unroll
    for (int c = 0; c < 4; ++c) {
        d[c][0] = __uint_as_float(q[c].x << 16);
        d[c][1] = __uint_as_float(q[c].x & 0xFFFF0000u);
        d[c][2] = __uint_as_float(q[c].y << 16);
        d[c][3] = __uint_as_float(q[c].y & 0xFFFF0000u);
        d[c][4] = __uint_as_float(q[c].z << 16);
        d[c][5] = __uint_as_float(q[c].z & 0xFFFF0000u);
        d[c][6] = __uint_as_float(q[c].w << 16);
        d[c][7] = __uint_as_float(q[c].w & 0xFFFF0000u);
    }
    int sp = s + 4; if (sp > HSLAB - 1) sp = HSLAB - 1;
    const uint4* pp = base + (size_t)sp * SLAB_U4;
    q[0] = pp[0]; q[1] = pp[1]; q[2] = pp[2]; q[3] = pp[3];

    float sv0 = V[7], sv1 = V[7], sv2 = V[7], sv3 = V[7];
    const bool act = HEAD ? (s >= lane) : (s - lane <= 63);

    if (act) {
        float dg0 = diag0;
        if (HEAD) {
            if (s == lane) dg0 = (lane == 0) ? 0.0f : BIGF;
        }
        float n[8][4];
        #pragma unroll
        for (int t = 0; t < 11; ++t) {
            #pragma unroll
            for (int c = 0; c < 4; ++c) {
                const int r = t - c;
                if (r >= 0 && r < 8) {
                    float A  = (r == 0) ? top[c] : n[r-1][c];
                    float Bv = (c == 0) ? V[r]   : n[r][c-1];
                    float Cv = (r == 0) ? ((c == 0) ? dg0    : top[c-1])
                                        : ((c == 0) ? V[r-1] : n[r-1][c-1]);
                    n[r][c] = d[c][r] + fminf(fminf(A, Bv), Cv);
                }
            }
        }
        #pragma unroll
        for (int r = 0; r < 8; ++r) V[r] = n[r][3];
        sv0 = n[7][0]; sv1 = n[7][1]; sv2 = n[7][2]; sv3 = n[7][3];
    }

    diag0 = top[3];
    float t0 = __shfl_up(sv0, 1);
    float t1 = __shfl_up(sv1, 1);
    float t2 = __shfl_up(sv2, 1);
    float t3 = __shfl_up(sv3, 1);
    const bool l0 = (lane == 0);
    top[0] = l0 ? BIGF : t0;
    top[1] = l0 ? BIGF : t1;
    top[2] = l0 ? BIGF : t2;
    top[3] = l0 ? BIGF : t3;
}

// ---------------------------------------------------------------------------
// Fused GEMM + DTW + combine. 576 blocks x 256 threads.
//   [0, 512):   GEMM tile (never waits — pre ran in the previous launch)
//   [512, 576): DTW half (polls ctrGemm[b] via atomicAdd RMW -> coherence
//               point, never stale L1); last finisher combines.
// Deadlock-free under any dispatch order/occupancy: waiters (<=64 blocks)
// only wait on non-waiters, and gemm always has free slots.
__global__ void __launch_bounds__(256) gemm_dtw_kernel(
    const ushort* __restrict__ xbf, const ushort* __restrict__ ybf,
    const float* __restrict__ x2, const float* __restrict__ y2,
    ushort* __restrict__ Dskew, float* __restrict__ bound,
    unsigned* __restrict__ ctrGemm, unsigned* __restrict__ done,
    float* __restrict__ out)
{
    const unsigned bid = blockIdx.x;

    if (bid < NGEMM) {
        // ------------------------------ GEMM -----------------------------
        const int b    = bid >> 4;
        const int tile = bid & 15;
        const int bi   = tile & 3;
        const int bj   = tile >> 2;

        const int w    = threadIdx.x >> 6;
        const int lane = threadIdx.x & 63;
        const int wi   = w & 1, wj = w >> 1;
        const int m    = lane & 15, g = lane >> 4;
        const int i0 = bi * 128 + wi * 64;
        const int j0 = bj * 128 + wj * 64;

        const ushort* xb = xbf + ((size_t)b * N_SZ + i0 + m) * D_SZ + 8 * g;
        const ushort* yb = ybf + ((size_t)b * M_SZ + j0 + m) * D_SZ + 8 * g;

        f32x4 acc[4][4] = {};
        for (int k0 = 0; k0 < D_SZ; k0 += 32) {
            short8 av[4], bv[4];
            #pragma unroll
            for (int f = 0; f < 4; ++f) {
                av[f] = *(const short8*)(xb + (size_t)f * 16 * D_SZ + k0);
                bv[f] = *(const short8*)(yb + (size_t)f * 16 * D_SZ + k0);
            }
            #pragma unroll
            for (int fi = 0; fi < 4; ++fi)
                #pragma unroll
                for (int fj = 0; fj < 4; ++fj)
                    acc[fi][fj] = __builtin_amdgcn_mfma_f32_16x16x32_bf16(
                                      av[fi], bv[fj], acc[fi][fj], 0, 0, 0);
        }

        const size_t bbase = (size_t)b * (2 * HALF_E);
        #pragma unroll
        for (int fi = 0; fi < 4; ++fi) {
            const int ib = i0 + fi * 16 + 4 * g;
            const float4 xv = *(const float4*)(x2 + b * N_SZ + ib);
            #pragma unroll
            for (int fj = 0; fj < 4; ++fj) {
                const int j = j0 + fj * 16 + m;
                const float y2v = y2[b * M_SZ + j];
                float d0 = (xv.x + y2v) - 2.0f * acc[fi][fj][0];
                float d1 = (xv.y + y2v) - 2.0f * acc[fi][fj][1];
                float d2 = (xv.z + y2v) - 2.0f * acc[fi][fj][2];
                float d3 = (xv.w + y2v) - 2.0f * acc[fi][fj][3];
                if (j0 + fj * 16 < 256) {
                    const int L = ib >> 3;
                    size_t off = bbase + (size_t)((j >> 2) + L) * 2048
                               + (size_t)L * 32 + (j & 3) * 8 + (ib & 7);
                    *(uint2*)(Dskew + off) = make_uint2(pack_bf16(d0, d1), pack_bf16(d2, d3));
                } else {
                    const int jr  = 511 - j;
                    const int irb = 508 - ib;
                    const int Lr  = irb >> 3;
                    size_t off = bbase + HALF_E + (size_t)((jr >> 2) + Lr) * 2048
                               + (size_t)Lr * 32 + (jr & 3) * 8 + (irb & 7);
                    *(uint2*)(Dskew + off) = make_uint2(pack_bf16(d3, d2), pack_bf16(d1, d0));
                }
            }
        }
        __syncthreads();
        if (threadIdx.x == 0) {
            __threadfence();                       // flush tile stores to coherence point
            atomicAdd(&ctrGemm[b], 1u);            // device-scope RMW (m20)
        }
        return;
    }

    // ------------------------------- DTW ---------------------------------
    if (threadIdx.x >= 64) return;        // 1 wave
    const int lane = threadIdx.x;
    const unsigned did = bid - NGEMM;
    const int h = did & 1;                // 0 = forward, 1 = reverse
    const int b = did >> 1;

    if (lane == 0) {
        while (atomicAdd(&ctrGemm[b], 0u) < 16u)   // RMW poll: always coherent
            __builtin_amdgcn_s_sleep(8);
    }
    __threadfence();                                // acquire: invalidate caches

    const uint4* base = (const uint4*)(Dskew + ((size_t)b * 2 + h) * HALF_E) + lane * 4;

    float V[8];
    #pragma unroll
    for (int r = 0; r < 8; ++r) V[r] = BIGF;
    float top[4] = {BIGF, BIGF, BIGF, BIGF};
    float diag0  = BIGF;

    uint4 qA[4], qB[4], qC[4], qD[4];
    { const uint4* p = base;               qA[0]=p[0]; qA[1]=p[1]; qA[2]=p[2]; qA[3]=p[3]; }
    { const uint4* p = base + 1*SLAB_U4;   qB[0]=p[0]; qB[1]=p[1]; qB[2]=p[2]; qB[3]=p[3]; }
    { const uint4* p = base + 2*SLAB_U4;   qC[0]=p[0]; qC[1]=p[1]; qC[2]=p[2]; qC[3]=p[3]; }
    { const uint4* p = base + 3*SLAB_U4;   qD[0]=p[0]; qD[1]=p[1]; qD[2]=p[2]; qD[3]=p[3]; }

    for (int s = 0; s < 64; s += 4) {
        dtw_step<true>(s + 0, lane, base, qA, V, top, diag0);
        dtw_step<true>(s + 1, lane, base, qB, V, top, diag0);
        dtw_step<true>(s + 2, lane, base, qC, V, top, diag0);
        dtw_step<true>(s + 3, lane, base, qD, V, top, diag0);
    }
    for (int s = 64; s < 128; s += 4) {
        dtw_step<false>(s + 0, lane, base, qA, V, top, diag0);
        dtw_step<false>(s + 1, lane, base, qB, V, top, diag0);
        dtw_step<false>(s + 2, lane, base, qC, V, top, diag0);
        dtw_step<false>(s + 3, lane, base, qD, V, top, diag0);
    }

    float* bptr = bound + ((size_t)b * 2 + h) * 512;
    if (h == 0) {
        *(float4*)(bptr + 8 * lane)     = make_float4(V[0], V[1], V[2], V[3]);
        *(float4*)(bptr + 8 * lane + 4) = make_float4(V[4], V[5], V[6], V[7]);
    } else {
        const int ibase = 504 - 8 * lane;
        *(float4*)(bptr + ibase)     = make_float4(V[7], V[6], V[5], V[4]);
        *(float4*)(bptr + ibase + 4) = make_float4(V[3], V[2], V[1], V[0]);
    }

    __threadfence();                                // release bound stores
    unsigned old = 0;
    if (lane == 0) old = atomicAdd(done, 1u);
    old = __shfl(old, 0);
    if (old == NDTW - 1) {
        __threadfence();                            // acquire all bound stores
        // last DTW block: combine. 2 lanes per batch, 256 i's each.
        const int cb  = lane >> 1;
        const int i0c = (lane & 1) * 256;
        const float* Fb = bound + (size_t)cb * 1024;
        const float* Bb = Fb + 512;
        float mv = BIGF;
        for (int k = 0; k < 256; ++k) {
            const int i = i0c + k;
            const float bn = (i == 511) ? Bb[511] : fminf(Bb[i], Bb[i + 1]);
            mv = fminf(mv, Fb[i] + bn);
        }
        mv = fminf(mv, __shfl_xor(mv, 1));          // pair-merge: batch min
        float v = ((lane & 1) == 0) ? mv : 0.0f;    // each batch counted once
        #pragma unroll
        for (int o = 32; o > 0; o >>= 1) v += __shfl_down(v, o);
        if (lane == 0) out[0] = v * (1.0f / B_SZ);
    }
}

// ---------------------------------------------------------------------------
extern "C" void kernel_launch(void* const* d_in, const int* in_sizes, int n_in,
                              void* d_out, int out_size, void* d_ws, size_t ws_size,
                              hipStream_t stream) {
    const float* x  = (const float*)d_in[0];   // (32,512,256)
    const float* te = (const float*)d_in[1];   // (32,512,1024)
    float* out = (float*)d_out;

    char* ws = (char*)d_ws;
    ushort* Dskew = (ushort*)(ws);                                   // 33.6MB
    ushort* ybf   = (ushort*)(ws + (size_t)B_SZ * 2 * HALF_E * 2);   // 8.4MB
    ushort* xbf   = ybf + (size_t)B_SZ * M_SZ * D_SZ;                // 8.4MB
    float*  x2    = (float*)(xbf + (size_t)B_SZ * N_SZ * D_SZ);
    float*  y2    = x2 + B_SZ * N_SZ;
    float*  bound = y2 + B_SZ * M_SZ;                                // 32*2*512 f32
    unsigned* ctrGemm = (unsigned*)(bound + B_SZ * 2 * 512);         // 32
    unsigned* done    = ctrGemm + B_SZ;                              // 1

    hipMemsetAsync(ctrGemm, 0, (B_SZ + 1) * sizeof(unsigned), stream);
    pre_kernel<<<16384 + 4096, 256, 0, stream>>>(te, x, ybf, xbf, y2, x2);
    gemm_dtw_kernel<<<NGEMM + NDTW, 256, 0, stream>>>(
        xbf, ybf, x2, y2, Dskew, bound, ctrGemm, done, out);
}

// Round 18
// 111.208 us; speedup vs baseline: 1.2335x; 1.2335x over previous
//
#include <hip/hip_runtime.h>
#include <hip/hip_bf16.h>
#include <stddef.h>

#define B_SZ   32
#define N_SZ   512
#define M_SZ   512
#define D_SZ   256
#define HSLAB  128           // slabs per half: s = (i>>3)+(j>>2), 0..126 (+1 pad)
#define SLAB_U4 256          // 2048 bf16 per slab = 256 uint4
#define HALF_E (HSLAB * 2048)  // elements per half
#define BIGF   1e10f
#define NDTW   64

typedef __attribute__((ext_vector_type(8))) short short8;
typedef __attribute__((ext_vector_type(4))) float f32x4;

__device__ __forceinline__ unsigned pack_bf16(float lo, float hi) {
    unsigned short a = __builtin_bit_cast(unsigned short, __float2bfloat16(lo));
    unsigned short b = __builtin_bit_cast(unsigned short, __float2bfloat16(hi));
    return (unsigned)a | ((unsigned)b << 16);
}

// ---------------------------------------------------------------------------
// Fused pre-pass (proven R15).
// Blocks 0..16383: teacher row -> ybf (mean-of-4, bf16) + y2 norm.
// Blocks 16384..20479: x rows -> xbf (bf16 copy) + x2 norms (4 rows/block).
__global__ void __launch_bounds__(256) pre_kernel(const float* __restrict__ t,
                                                  const float* __restrict__ x,
                                                  ushort* __restrict__ ybf,
                                                  ushort* __restrict__ xbf,
                                                  float* __restrict__ y2,
                                                  float* __restrict__ x2) {
    if (blockIdx.x < 16384) {
        const int row = blockIdx.x;
        const int c   = threadIdx.x;
        float4 v = *((const float4*)t + (size_t)row * 256 + c);
        float m = (v.x + v.y + v.z + v.w) * 0.25f;
        ybf[(size_t)row * 256 + c] = __builtin_bit_cast(unsigned short, __float2bfloat16(m));
        float s = m * m;
        #pragma unroll
        for (int o = 32; o > 0; o >>= 1) s += __shfl_down(s, o);
        __shared__ float acc4[4];
        if ((c & 63) == 0) acc4[c >> 6] = s;
        __syncthreads();
        if (c == 0) y2[row] = (acc4[0] + acc4[1]) + (acc4[2] + acc4[3]);
    } else {
        const int wave = threadIdx.x >> 6;
        const int lane = threadIdx.x & 63;
        const int row  = (blockIdx.x - 16384) * 4 + wave;
        const float4* r4 = (const float4*)(x + (size_t)row * D_SZ);
        float4 v = r4[lane];
        *(uint2*)(xbf + (size_t)row * D_SZ + lane * 4) =
            make_uint2(pack_bf16(v.x, v.y), pack_bf16(v.z, v.w));
        float s = v.x*v.x + v.y*v.y + v.z*v.z + v.w*v.w;
        #pragma unroll
        for (int o = 32; o > 0; o >>= 1) s += __shfl_down(s, o);
        if (lane == 0) x2[row] = s;
    }
}

// ---------------------------------------------------------------------------
// bf16 MFMA distance GEMM (proven R15), split-skew bf16 output:
//  FWD half (j<256):  slab s=(j>>2)+(i>>3); elem s*2048 + (i>>3)*32 + (j&3)*8 + (i&7)
//  REV half (j>=256): i_r=511-i, j_r=511-j, same formula on (i_r,j_r), +HALF_E.
__global__ void __launch_bounds__(256) gemm_kernel(const ushort* __restrict__ xbf,
                                                   const ushort* __restrict__ ybf,
                                                   const float* __restrict__ x2,
                                                   const float* __restrict__ y2,
                                                   ushort* __restrict__ Dskew) {
    const int b    = blockIdx.z;
    const int bi   = blockIdx.x;
    const int bj   = blockIdx.y;
    const int w    = threadIdx.x >> 6;
    const int lane = threadIdx.x & 63;
    const int wi   = w & 1, wj = w >> 1;
    const int m    = lane & 15, g = lane >> 4;

    const int i0 = bi * 128 + wi * 64;
    const int j0 = bj * 128 + wj * 64;

    const ushort* xb = xbf + ((size_t)b * N_SZ + i0 + m) * D_SZ + 8 * g;
    const ushort* yb = ybf + ((size_t)b * M_SZ + j0 + m) * D_SZ + 8 * g;

    f32x4 acc[4][4] = {};

    for (int k0 = 0; k0 < D_SZ; k0 += 32) {
        short8 av[4], bv[4];
        #pragma unroll
        for (int f = 0; f < 4; ++f) {
            av[f] = *(const short8*)(xb + (size_t)f * 16 * D_SZ + k0);
            bv[f] = *(const short8*)(yb + (size_t)f * 16 * D_SZ + k0);
        }
        #pragma unroll
        for (int fi = 0; fi < 4; ++fi)
            #pragma unroll
            for (int fj = 0; fj < 4; ++fj)
                acc[fi][fj] = __builtin_amdgcn_mfma_f32_16x16x32_bf16(
                                  av[fi], bv[fj], acc[fi][fj], 0, 0, 0);
    }

    const size_t bbase = (size_t)b * (2 * HALF_E);
    #pragma unroll
    for (int fi = 0; fi < 4; ++fi) {
        const int ib = i0 + fi * 16 + 4 * g;          // 4 consecutive i in one 8-block
        const float4 xv = *(const float4*)(x2 + b * N_SZ + ib);
        #pragma unroll
        for (int fj = 0; fj < 4; ++fj) {
            const int j = j0 + fj * 16 + m;
            const float y2v = y2[b * M_SZ + j];
            float d0 = (xv.x + y2v) - 2.0f * acc[fi][fj][0];
            float d1 = (xv.y + y2v) - 2.0f * acc[fi][fj][1];
            float d2 = (xv.z + y2v) - 2.0f * acc[fi][fj][2];
            float d3 = (xv.w + y2v) - 2.0f * acc[fi][fj][3];
            if (j0 + fj * 16 < 256) {                 // uniform per fj-block
                const int L = ib >> 3;
                size_t off = bbase + (size_t)((j >> 2) + L) * 2048
                           + (size_t)L * 32 + (j & 3) * 8 + (ib & 7);
                *(uint2*)(Dskew + off) = make_uint2(pack_bf16(d0, d1), pack_bf16(d2, d3));
            } else {
                const int jr  = 511 - j;
                const int irb = 508 - ib;             // i_r of i = ib+3 (ascending base)
                const int Lr  = irb >> 3;
                size_t off = bbase + HALF_E + (size_t)((jr >> 2) + Lr) * 2048
                           + (size_t)Lr * 32 + (jr & 3) * 8 + (irb & 7);
                *(uint2*)(Dskew + off) = make_uint2(pack_bf16(d3, d2), pack_bf16(d1, d0));
            }
        }
    }
}

// ---------------------------------------------------------------------------
// Meet-in-the-middle DTW half (proven R15: one wave/block, 4-deep prefetch)
// + combine folded into the LAST-FINISHING block (pattern verified in R17).
template <bool HEAD>
__device__ __forceinline__ void dtw_step(int s, int lane,
    const uint4* __restrict__ base, uint4 (&q)[4],
    float (&V)[8], float (&top)[4], float& diag0)
{
    float d[4][8];
    #pragma unroll
    for (int c = 0; c < 4; ++c) {
        d[c][0] = __uint_as_float(q[c].x << 16);
        d[c][1] = __uint_as_float(q[c].x & 0xFFFF0000u);
        d[c][2] = __uint_as_float(q[c].y << 16);
        d[c][3] = __uint_as_float(q[c].y & 0xFFFF0000u);
        d[c][4] = __uint_as_float(q[c].z << 16);
        d[c][5] = __uint_as_float(q[c].z & 0xFFFF0000u);
        d[c][6] = __uint_as_float(q[c].w << 16);
        d[c][7] = __uint_as_float(q[c].w & 0xFFFF0000u);
    }
    int sp = s + 4; if (sp > HSLAB - 1) sp = HSLAB - 1;
    const uint4* pp = base + (size_t)sp * SLAB_U4;
    q[0] = pp[0]; q[1] = pp[1]; q[2] = pp[2]; q[3] = pp[3];

    float sv0 = V[7], sv1 = V[7], sv2 = V[7], sv3 = V[7];
    const bool act = HEAD ? (s >= lane) : (s - lane <= 63);

    if (act) {
        float dg0 = diag0;
        if (HEAD) {
            if (s == lane) dg0 = (lane == 0) ? 0.0f : BIGF;
        }
        float n[8][4];
        #pragma unroll
        for (int t = 0; t < 11; ++t) {
            #pragma unroll
            for (int c = 0; c < 4; ++c) {
                const int r = t - c;
                if (r >= 0 && r < 8) {
                    float A  = (r == 0) ? top[c] : n[r-1][c];
                    float Bv = (c == 0) ? V[r]   : n[r][c-1];
                    float Cv = (r == 0) ? ((c == 0) ? dg0    : top[c-1])
                                        : ((c == 0) ? V[r-1] : n[r-1][c-1]);
                    n[r][c] = d[c][r] + fminf(fminf(A, Bv), Cv);
                }
            }
        }
        #pragma unroll
        for (int r = 0; r < 8; ++r) V[r] = n[r][3];
        sv0 = n[7][0]; sv1 = n[7][1]; sv2 = n[7][2]; sv3 = n[7][3];
    }

    diag0 = top[3];
    float t0 = __shfl_up(sv0, 1);
    float t1 = __shfl_up(sv1, 1);
    float t2 = __shfl_up(sv2, 1);
    float t3 = __shfl_up(sv3, 1);
    const bool l0 = (lane == 0);
    top[0] = l0 ? BIGF : t0;
    top[1] = l0 ? BIGF : t1;
    top[2] = l0 ? BIGF : t2;
    top[3] = l0 ? BIGF : t3;
}

__global__ void __launch_bounds__(64) dtw_kernel(const ushort* __restrict__ Dskew,
                                                 float* __restrict__ bound,
                                                 unsigned* __restrict__ done,
                                                 float* __restrict__ out) {
    const int lane = threadIdx.x;
    const int h    = blockIdx.x;          // 0 = forward, 1 = reverse
    const int b    = blockIdx.y;
    const uint4* base = (const uint4*)(Dskew + ((size_t)b * 2 + h) * HALF_E) + lane * 4;

    float V[8];
    #pragma unroll
    for (int r = 0; r < 8; ++r) V[r] = BIGF;
    float top[4] = {BIGF, BIGF, BIGF, BIGF};
    float diag0  = BIGF;

    uint4 qA[4], qB[4], qC[4], qD[4];
    { const uint4* p = base;               qA[0]=p[0]; qA[1]=p[1]; qA[2]=p[2]; qA[3]=p[3]; }
    { const uint4* p = base + 1*SLAB_U4;   qB[0]=p[0]; qB[1]=p[1]; qB[2]=p[2]; qB[3]=p[3]; }
    { const uint4* p = base + 2*SLAB_U4;   qC[0]=p[0]; qC[1]=p[1]; qC[2]=p[2]; qC[3]=p[3]; }
    { const uint4* p = base + 3*SLAB_U4;   qD[0]=p[0]; qD[1]=p[1]; qD[2]=p[2]; qD[3]=p[3]; }

    for (int s = 0; s < 64; s += 4) {      // head: t>=0 guard + t==0 corner
        dtw_step<true>(s + 0, lane, base, qA, V, top, diag0);
        dtw_step<true>(s + 1, lane, base, qB, V, top, diag0);
        dtw_step<true>(s + 2, lane, base, qC, V, top, diag0);
        dtw_step<true>(s + 3, lane, base, qD, V, top, diag0);
    }
    for (int s = 64; s < 128; s += 4) {    // tail: t<=63 guard (s=127 = pad step)
        dtw_step<false>(s + 0, lane, base, qA, V, top, diag0);
        dtw_step<false>(s + 1, lane, base, qB, V, top, diag0);
        dtw_step<false>(s + 2, lane, base, qC, V, top, diag0);
        dtw_step<false>(s + 3, lane, base, qD, V, top, diag0);
    }

    // write boundary: h=0 -> F(8L+r, 255) at [8L+r]; h=1 -> B(i,256) at [i],
    // where V[r] corresponds to original row i = 511-(8L+r).
    float* bptr = bound + ((size_t)b * 2 + h) * 512;
    if (h == 0) {
        *(float4*)(bptr + 8 * lane)     = make_float4(V[0], V[1], V[2], V[3]);
        *(float4*)(bptr + 8 * lane + 4) = make_float4(V[4], V[5], V[6], V[7]);
    } else {
        const int ibase = 504 - 8 * lane;
        *(float4*)(bptr + ibase)     = make_float4(V[7], V[6], V[5], V[4]);
        *(float4*)(bptr + ibase + 4) = make_float4(V[3], V[2], V[1], V[0]);
    }

    // last-finisher combine (pattern verified correct in R17; no spin-wait)
    __threadfence();                               // release bound stores
    unsigned old = 0;
    if (lane == 0) old = atomicAdd(done, 1u);
    old = __shfl(old, 0);
    if (old == NDTW - 1) {
        __threadfence();                           // acquire all bound stores
        const int cb  = lane >> 1;                 // 2 lanes per batch
        const int i0c = (lane & 1) * 256;
        const float* Fb = bound + (size_t)cb * 1024;
        const float* Bb = Fb + 512;
        float mv = BIGF;
        for (int k = 0; k < 256; ++k) {
            const int i = i0c + k;
            const float bn = (i == 511) ? Bb[511] : fminf(Bb[i], Bb[i + 1]);
            mv = fminf(mv, Fb[i] + bn);
        }
        mv = fminf(mv, __shfl_xor(mv, 1));          // pair-merge: batch min
        float v = ((lane & 1) == 0) ? mv : 0.0f;    // each batch counted once
        #pragma unroll
        for (int o = 32; o > 0; o >>= 1) v += __shfl_down(v, o);
        if (lane == 0) out[0] = v * (1.0f / B_SZ);
    }
}

// ---------------------------------------------------------------------------
extern "C" void kernel_launch(void* const* d_in, const int* in_sizes, int n_in,
                              void* d_out, int out_size, void* d_ws, size_t ws_size,
                              hipStream_t stream) {
    const float* x  = (const float*)d_in[0];   // (32,512,256)
    const float* te = (const float*)d_in[1];   // (32,512,1024)
    float* out = (float*)d_out;

    char* ws = (char*)d_ws;
    ushort* Dskew = (ushort*)(ws);                                   // 33.6MB
    ushort* ybf   = (ushort*)(ws + (size_t)B_SZ * 2 * HALF_E * 2);   // 8.4MB
    ushort* xbf   = ybf + (size_t)B_SZ * M_SZ * D_SZ;                // 8.4MB
    float*  x2    = (float*)(xbf + (size_t)B_SZ * N_SZ * D_SZ);
    float*  y2    = x2 + B_SZ * N_SZ;
    float*  bound = y2 + B_SZ * M_SZ;                                // 32*2*512 f32
    unsigned* done = (unsigned*)(bound + B_SZ * 2 * 512);            // 1

    hipMemsetAsync(done, 0, sizeof(unsigned), stream);
    pre_kernel<<<16384 + 4096, 256, 0, stream>>>(te, x, ybf, xbf, y2, x2);
    gemm_kernel<<<dim3(N_SZ/128, M_SZ/128, B_SZ), 256, 0, stream>>>(xbf, ybf, x2, y2, Dskew);
    dtw_kernel<<<dim3(2, B_SZ), 64, 0, stream>>>(Dskew, bound, done, out);
}

// Round 19
// 101.990 us; speedup vs baseline: 1.3450x; 1.0904x over previous
//
#include <hip/hip_runtime.h>
#include <hip/hip_bf16.h>
#include <stddef.h>

#define B_SZ   32
#define N_SZ   512
#define M_SZ   512
#define D_SZ   256
#define NSLAB  96            // slabs: s = (i>>4) + (j>>2), 0..94 (+1 pad)
#define SLAB_E 4096          // bf16 per slab: 2 problems x 32 lanes x 64
#define SLAB_U4 512          // uint4 per slab
#define BIGF   1e10f

typedef __attribute__((ext_vector_type(8))) short short8;
typedef __attribute__((ext_vector_type(4))) float f32x4;

__device__ __forceinline__ unsigned pack_bf16(float lo, float hi) {
    unsigned short a = __builtin_bit_cast(unsigned short, __float2bfloat16(lo));
    unsigned short b = __builtin_bit_cast(unsigned short, __float2bfloat16(hi));
    return (unsigned)a | ((unsigned)b << 16);
}

// ---------------------------------------------------------------------------
// Fused pre-pass (proven R15).
__global__ void __launch_bounds__(256) pre_kernel(const float* __restrict__ t,
                                                  const float* __restrict__ x,
                                                  ushort* __restrict__ ybf,
                                                  ushort* __restrict__ xbf,
                                                  float* __restrict__ y2,
                                                  float* __restrict__ x2) {
    if (blockIdx.x < 16384) {
        const int row = blockIdx.x;
        const int c   = threadIdx.x;
        float4 v = *((const float4*)t + (size_t)row * 256 + c);
        float m = (v.x + v.y + v.z + v.w) * 0.25f;
        ybf[(size_t)row * 256 + c] = __builtin_bit_cast(unsigned short, __float2bfloat16(m));
        float s = m * m;
        #pragma unroll
        for (int o = 32; o > 0; o >>= 1) s += __shfl_down(s, o);
        __shared__ float acc4[4];
        if ((c & 63) == 0) acc4[c >> 6] = s;
        __syncthreads();
        if (c == 0) y2[row] = (acc4[0] + acc4[1]) + (acc4[2] + acc4[3]);
    } else {
        const int wave = threadIdx.x >> 6;
        const int lane = threadIdx.x & 63;
        const int row  = (blockIdx.x - 16384) * 4 + wave;
        const float4* r4 = (const float4*)(x + (size_t)row * D_SZ);
        float4 v = r4[lane];
        *(uint2*)(xbf + (size_t)row * D_SZ + lane * 4) =
            make_uint2(pack_bf16(v.x, v.y), pack_bf16(v.z, v.w));
        float s = v.x*v.x + v.y*v.y + v.z*v.z + v.w*v.w;
        #pragma unroll
        for (int o = 32; o > 0; o >>= 1) s += __shfl_down(s, o);
        if (lane == 0) x2[row] = s;
    }
}

// ---------------------------------------------------------------------------
// bf16 MFMA distance GEMM; new 16-row-lane split-skew output.
//  FWD (j<256):  L=i>>4, s=(j>>2)+L; elem s*4096 + L*64 + (j&3)*16 + (i&15)
//  REV (j>=256): i_r=511-i, j_r=511-j, same formula on (i_r,j_r), +2048.
__global__ void __launch_bounds__(256) gemm_kernel(const ushort* __restrict__ xbf,
                                                   const ushort* __restrict__ ybf,
                                                   const float* __restrict__ x2,
                                                   const float* __restrict__ y2,
                                                   ushort* __restrict__ Dskew) {
    const int b    = blockIdx.z;
    const int bi   = blockIdx.x;
    const int bj   = blockIdx.y;
    const int w    = threadIdx.x >> 6;
    const int lane = threadIdx.x & 63;
    const int wi   = w & 1, wj = w >> 1;
    const int m    = lane & 15, g = lane >> 4;

    const int i0 = bi * 128 + wi * 64;
    const int j0 = bj * 128 + wj * 64;

    const ushort* xb = xbf + ((size_t)b * N_SZ + i0 + m) * D_SZ + 8 * g;
    const ushort* yb = ybf + ((size_t)b * M_SZ + j0 + m) * D_SZ + 8 * g;

    f32x4 acc[4][4] = {};

    for (int k0 = 0; k0 < D_SZ; k0 += 32) {
        short8 av[4], bv[4];
        #pragma unroll
        for (int f = 0; f < 4; ++f) {
            av[f] = *(const short8*)(xb + (size_t)f * 16 * D_SZ + k0);
            bv[f] = *(const short8*)(yb + (size_t)f * 16 * D_SZ + k0);
        }
        #pragma unroll
        for (int fi = 0; fi < 4; ++fi)
            #pragma unroll
            for (int fj = 0; fj < 4; ++fj)
                acc[fi][fj] = __builtin_amdgcn_mfma_f32_16x16x32_bf16(
                                  av[fi], bv[fj], acc[fi][fj], 0, 0, 0);
    }

    const size_t bbase = (size_t)b * NSLAB * SLAB_E;
    #pragma unroll
    for (int fi = 0; fi < 4; ++fi) {
        const int ib = i0 + fi * 16 + 4 * g;          // 4 consecutive i
        const float4 xv = *(const float4*)(x2 + b * N_SZ + ib);
        #pragma unroll
        for (int fj = 0; fj < 4; ++fj) {
            const int j = j0 + fj * 16 + m;
            const float y2v = y2[b * M_SZ + j];
            float d0 = (xv.x + y2v) - 2.0f * acc[fi][fj][0];
            float d1 = (xv.y + y2v) - 2.0f * acc[fi][fj][1];
            float d2 = (xv.z + y2v) - 2.0f * acc[fi][fj][2];
            float d3 = (xv.w + y2v) - 2.0f * acc[fi][fj][3];
            if (j0 + fj * 16 < 256) {                 // uniform per fj-block
                const int L = ib >> 4;
                size_t off = bbase + (size_t)((j >> 2) + L) * SLAB_E
                           + (size_t)L * 64 + (j & 3) * 16 + (ib & 15);
                *(uint2*)(Dskew + off) = make_uint2(pack_bf16(d0, d1), pack_bf16(d2, d3));
            } else {
                const int jr  = 511 - j;
                const int irb = 508 - ib;             // ascending base of reversed i
                const int Lr  = irb >> 4;
                size_t off = bbase + (size_t)((jr >> 2) + Lr) * SLAB_E + 2048
                           + (size_t)Lr * 64 + (jr & 3) * 16 + (irb & 15);
                *(uint2*)(Dskew + off) = make_uint2(pack_bf16(d3, d2), pack_bf16(d1, d0));
            }
        }
    }
}

// ---------------------------------------------------------------------------
// DTW: one wave per BATCH; lanes 0-31 = forward half, lanes 32-63 = reverse
// half (identical recurrence, reversed data). Lane owns 16 rows; chunk = 4
// cols; chunk t = s - p at step s (p = lane&31). 96 steps. 4-deep prefetch.
// Combine is fully in-register via shfl_xor(…, 63) at the end.
template <int PHASE>
__device__ __forceinline__ void dtw_step(int s, int p, bool lz,
    const uint4* __restrict__ base, uint4 (&q)[8],
    float (&V)[16], float (&top)[4], float& diag0)
{
    float d[4][16];
    #pragma unroll
    for (int u = 0; u < 8; ++u) {
        const int c = u >> 1, r0 = (u & 1) * 8;
        d[c][r0+0] = __uint_as_float(q[u].x << 16);
        d[c][r0+1] = __uint_as_float(q[u].x & 0xFFFF0000u);
        d[c][r0+2] = __uint_as_float(q[u].y << 16);
        d[c][r0+3] = __uint_as_float(q[u].y & 0xFFFF0000u);
        d[c][r0+4] = __uint_as_float(q[u].z << 16);
        d[c][r0+5] = __uint_as_float(q[u].z & 0xFFFF0000u);
        d[c][r0+6] = __uint_as_float(q[u].w << 16);
        d[c][r0+7] = __uint_as_float(q[u].w & 0xFFFF0000u);
    }
    int sp = s + 4; if (sp > NSLAB - 1) sp = NSLAB - 1;
    const uint4* pp = base + (size_t)sp * SLAB_U4;
    #pragma unroll
    for (int u = 0; u < 8; ++u) q[u] = pp[u];

    float sv0 = V[15], sv1 = V[15], sv2 = V[15], sv3 = V[15];

    bool act;
    if (PHASE == 0)      act = (s >= p);          // head: t >= 0
    else if (PHASE == 1) act = true;              // middle: 1 <= t <= 63
    else                 act = (s - p <= 63);     // tail: t <= 63

    if (act) {
        float dg0 = diag0;
        if (PHASE == 0) {
            if (s == p) dg0 = lz ? 0.0f : BIGF;   // chunk 0; both DPs start at 0
        }
        float n[16][4];
        #pragma unroll
        for (int t = 0; t < 19; ++t) {
            #pragma unroll
            for (int c = 0; c < 4; ++c) {
                const int r = t - c;
                if (r >= 0 && r < 16) {
                    float A  = (r == 0) ? top[c] : n[r-1][c];
                    float Bv = (c == 0) ? V[r]   : n[r][c-1];
                    float Cv = (r == 0) ? ((c == 0) ? dg0    : top[c-1])
                                        : ((c == 0) ? V[r-1] : n[r-1][c-1]);
                    n[r][c] = d[c][r] + fminf(fminf(A, Bv), Cv);
                }
            }
        }
        #pragma unroll
        for (int r = 0; r < 16; ++r) V[r] = n[r][3];
        sv0 = n[15][0]; sv1 = n[15][1]; sv2 = n[15][2]; sv3 = n[15][3];
    }

    diag0 = top[3];
    float t0 = __shfl_up(sv0, 1);
    float t1 = __shfl_up(sv1, 1);
    float t2 = __shfl_up(sv2, 1);
    float t3 = __shfl_up(sv3, 1);
    top[0] = lz ? BIGF : t0;      // masks lane 0 AND lane 32 (problem edge)
    top[1] = lz ? BIGF : t1;
    top[2] = lz ? BIGF : t2;
    top[3] = lz ? BIGF : t3;
}

__global__ void __launch_bounds__(64, 1) dtw_kernel(const ushort* __restrict__ Dskew,
                                                    float* __restrict__ part,
                                                    unsigned* __restrict__ done,
                                                    float* __restrict__ out) {
    const int lane = threadIdx.x;
    const int p    = lane & 31;
    const bool lz  = (p == 0);
    const int b    = blockIdx.x;
    const uint4* base = (const uint4*)(Dskew + (size_t)b * NSLAB * SLAB_E)
                      + ((lane >= 32) ? 256 : 0) + p * 8;

    float V[16];
    #pragma unroll
    for (int r = 0; r < 16; ++r) V[r] = BIGF;
    float top[4] = {BIGF, BIGF, BIGF, BIGF};
    float diag0  = BIGF;

    uint4 qA[8], qB[8], qC[8], qD[8];
    { const uint4* pp = base;             
      #pragma unroll
      for (int u = 0; u < 8; ++u) qA[u] = pp[u]; }
    { const uint4* pp = base + 1*SLAB_U4; 
      #pragma unroll
      for (int u = 0; u < 8; ++u) qB[u] = pp[u]; }
    { const uint4* pp = base + 2*SLAB_U4; 
      #pragma unroll
      for (int u = 0; u < 8; ++u) qC[u] = pp[u]; }
    { const uint4* pp = base + 3*SLAB_U4; 
      #pragma unroll
      for (int u = 0; u < 8; ++u) qD[u] = pp[u]; }

    for (int s = 0; s < 32; s += 4) {      // head: t>=0 guard + corner
        dtw_step<0>(s + 0, p, lz, base, qA, V, top, diag0);
        dtw_step<0>(s + 1, p, lz, base, qB, V, top, diag0);
        dtw_step<0>(s + 2, p, lz, base, qC, V, top, diag0);
        dtw_step<0>(s + 3, p, lz, base, qD, V, top, diag0);
    }
    for (int s = 32; s < 64; s += 4) {     // middle: all active
        dtw_step<1>(s + 0, p, lz, base, qA, V, top, diag0);
        dtw_step<1>(s + 1, p, lz, base, qB, V, top, diag0);
        dtw_step<1>(s + 2, p, lz, base, qC, V, top, diag0);
        dtw_step<1>(s + 3, p, lz, base, qD, V, top, diag0);
    }
    for (int s = 64; s < 96; s += 4) {     // tail: t<=63 guard (s=95 = pad)
        dtw_step<2>(s + 0, p, lz, base, qA, V, top, diag0);
        dtw_step<2>(s + 1, p, lz, base, qB, V, top, diag0);
        dtw_step<2>(s + 2, p, lz, base, qC, V, top, diag0);
        dtw_step<2>(s + 3, p, lz, base, qD, V, top, diag0);
    }

    // In-register combine.
    // fwd lane p: V[r] = F(16p+r, 255). rev lane 63-p: V[15-r] = B(16p+r, 256).
    float Bv[16];
    #pragma unroll
    for (int r = 0; r < 16; ++r) Bv[r] = __shfl_xor(V[15 - r], 63);
    float bn15 = __shfl_down(Bv[0], 1);    // B(16(p+1)) from lane p+1
    if (lane == 31) bn15 = BIGF;           // i+1 = 512: no such row
    float mv = BIGF;
    #pragma unroll
    for (int r = 0; r < 16; ++r) {
        float bn = (r < 15) ? Bv[r + 1] : bn15;
        mv = fminf(mv, V[r] + fminf(Bv[r], bn));
    }
    if (lane >= 32) mv = BIGF;
    #pragma unroll
    for (int o = 32; o > 0; o >>= 1) mv = fminf(mv, __shfl_xor(mv, o));

    unsigned old = 0;
    if (lane == 0) {
        __hip_atomic_exchange(&part[b], mv, __ATOMIC_RELAXED, __HIP_MEMORY_SCOPE_AGENT);
        old = __hip_atomic_fetch_add(done, 1u, __ATOMIC_ACQ_REL, __HIP_MEMORY_SCOPE_AGENT);
    }
    old = __shfl(old, 0);
    if (old == B_SZ - 1) {                 // last finisher: 32-float reduce
        float v = (lane < B_SZ)
                ? __hip_atomic_fetch_add(&part[lane], 0.0f, __ATOMIC_RELAXED, __HIP_MEMORY_SCOPE_AGENT)
                : 0.0f;
        #pragma unroll
        for (int o = 32; o > 0; o >>= 1) v += __shfl_down(v, o);
        if (lane == 0) out[0] = v * (1.0f / B_SZ);
    }
}

// ---------------------------------------------------------------------------
extern "C" void kernel_launch(void* const* d_in, const int* in_sizes, int n_in,
                              void* d_out, int out_size, void* d_ws, size_t ws_size,
                              hipStream_t stream) {
    const float* x  = (const float*)d_in[0];   // (32,512,256)
    const float* te = (const float*)d_in[1];   // (32,512,1024)
    float* out = (float*)d_out;

    char* ws = (char*)d_ws;
    ushort* Dskew = (ushort*)(ws);                                   // 32*96*4096 bf16 = 25.2MB
    ushort* ybf   = (ushort*)(ws + (size_t)B_SZ * NSLAB * SLAB_E * 2); // 8.4MB
    ushort* xbf   = ybf + (size_t)B_SZ * M_SZ * D_SZ;                // 8.4MB
    float*  x2    = (float*)(xbf + (size_t)B_SZ * N_SZ * D_SZ);
    float*  y2    = x2 + B_SZ * N_SZ;
    float*  part  = y2 + B_SZ * M_SZ;                                // 32 f32
    unsigned* done = (unsigned*)(part + B_SZ);                       // 1 u32

    hipMemsetAsync(done, 0, sizeof(unsigned), stream);
    pre_kernel<<<16384 + 4096, 256, 0, stream>>>(te, x, ybf, xbf, y2, x2);
    gemm_kernel<<<dim3(N_SZ/128, M_SZ/128, B_SZ), 256, 0, stream>>>(xbf, ybf, x2, y2, Dskew);
    dtw_kernel<<<B_SZ, 64, 0, stream>>>(Dskew, part, done, out);
}

// Round 20
// 88.631 us; speedup vs baseline: 1.5477x; 1.1507x over previous
//
#include <hip/hip_runtime.h>
#include <hip/hip_bf16.h>
#include <stddef.h>

#define B_SZ   32
#define N_SZ   512
#define M_SZ   512
#define D_SZ   256
#define HSLAB  128           // slabs per half: s = (i>>3)+(j>>2), 0..126 (+1 pad)
#define SLAB_U4 256          // 2048 bf16 per slab = 256 uint4
#define HALF_E (HSLAB * 2048)  // elements per half
#define BIGF   1e10f

typedef __attribute__((ext_vector_type(8))) short short8;
typedef __attribute__((ext_vector_type(4))) float f32x4;

__device__ __forceinline__ unsigned pack_bf16(float lo, float hi) {
    unsigned short a = __builtin_bit_cast(unsigned short, __float2bfloat16(lo));
    unsigned short b = __builtin_bit_cast(unsigned short, __float2bfloat16(hi));
    return (unsigned)a | ((unsigned)b << 16);
}

// ---------------------------------------------------------------------------
// Fused pre-pass.
// Blocks 0..16383: teacher row -> ybf (mean-of-4, bf16) + y2 norm.
// Blocks 16384..20479: x rows -> xbf (bf16 copy) + x2 norms (4 rows/block).
__global__ void __launch_bounds__(256) pre_kernel(const float* __restrict__ t,
                                                  const float* __restrict__ x,
                                                  ushort* __restrict__ ybf,
                                                  ushort* __restrict__ xbf,
                                                  float* __restrict__ y2,
                                                  float* __restrict__ x2) {
    if (blockIdx.x < 16384) {
        const int row = blockIdx.x;
        const int c   = threadIdx.x;
        float4 v = *((const float4*)t + (size_t)row * 256 + c);
        float m = (v.x + v.y + v.z + v.w) * 0.25f;
        ybf[(size_t)row * 256 + c] = __builtin_bit_cast(unsigned short, __float2bfloat16(m));
        float s = m * m;
        #pragma unroll
        for (int o = 32; o > 0; o >>= 1) s += __shfl_down(s, o);
        __shared__ float acc4[4];
        if ((c & 63) == 0) acc4[c >> 6] = s;
        __syncthreads();
        if (c == 0) y2[row] = (acc4[0] + acc4[1]) + (acc4[2] + acc4[3]);
    } else {
        const int wave = threadIdx.x >> 6;
        const int lane = threadIdx.x & 63;
        const int row  = (blockIdx.x - 16384) * 4 + wave;
        const float4* r4 = (const float4*)(x + (size_t)row * D_SZ);
        float4 v = r4[lane];
        *(uint2*)(xbf + (size_t)row * D_SZ + lane * 4) =
            make_uint2(pack_bf16(v.x, v.y), pack_bf16(v.z, v.w));
        float s = v.x*v.x + v.y*v.y + v.z*v.z + v.w*v.w;
        #pragma unroll
        for (int o = 32; o > 0; o >>= 1) s += __shfl_down(s, o);
        if (lane == 0) x2[row] = s;
    }
}

// ---------------------------------------------------------------------------
// bf16 MFMA distance GEMM (no LDS, pure-bf16 fragment loads straight from
// global — identical addressing for A and B), split-skew bf16 output:
//  FWD half (j<256):  slab s=(j>>2)+(i>>3); elem s*2048 + (i>>3)*32 + (j&3)*8 + (i&7)
//  REV half (j>=256): i_r=511-i, j_r=511-j, same formula on (i_r,j_r), +HALF_E.
__global__ void __launch_bounds__(256) gemm_kernel(const ushort* __restrict__ xbf,
                                                   const ushort* __restrict__ ybf,
                                                   const float* __restrict__ x2,
                                                   const float* __restrict__ y2,
                                                   ushort* __restrict__ Dskew) {
    const int b    = blockIdx.z;
    const int bi   = blockIdx.x;
    const int bj   = blockIdx.y;
    const int w    = threadIdx.x >> 6;
    const int lane = threadIdx.x & 63;
    const int wi   = w & 1, wj = w >> 1;
    const int m    = lane & 15, g = lane >> 4;

    const int i0 = bi * 128 + wi * 64;
    const int j0 = bj * 128 + wj * 64;

    const ushort* xb = xbf + ((size_t)b * N_SZ + i0 + m) * D_SZ + 8 * g;
    const ushort* yb = ybf + ((size_t)b * M_SZ + j0 + m) * D_SZ + 8 * g;

    f32x4 acc[4][4] = {};

    for (int k0 = 0; k0 < D_SZ; k0 += 32) {
        short8 av[4], bv[4];
        #pragma unroll
        for (int f = 0; f < 4; ++f) {
            av[f] = *(const short8*)(xb + (size_t)f * 16 * D_SZ + k0);
            bv[f] = *(const short8*)(yb + (size_t)f * 16 * D_SZ + k0);
        }
        #pragma unroll
        for (int fi = 0; fi < 4; ++fi)
            #pragma unroll
            for (int fj = 0; fj < 4; ++fj)
                acc[fi][fj] = __builtin_amdgcn_mfma_f32_16x16x32_bf16(
                                  av[fi], bv[fj], acc[fi][fj], 0, 0, 0);
    }

    const size_t bbase = (size_t)b * (2 * HALF_E);
    #pragma unroll
    for (int fi = 0; fi < 4; ++fi) {
        const int ib = i0 + fi * 16 + 4 * g;          // 4 consecutive i in one 8-block
        const float4 xv = *(const float4*)(x2 + b * N_SZ + ib);
        #pragma unroll
        for (int fj = 0; fj < 4; ++fj) {
            const int j = j0 + fj * 16 + m;
            const float y2v = y2[b * M_SZ + j];
            float d0 = (xv.x + y2v) - 2.0f * acc[fi][fj][0];
            float d1 = (xv.y + y2v) - 2.0f * acc[fi][fj][1];
            float d2 = (xv.z + y2v) - 2.0f * acc[fi][fj][2];
            float d3 = (xv.w + y2v) - 2.0f * acc[fi][fj][3];
            if (j0 + fj * 16 < 256) {                 // uniform per fj-block
                const int L = ib >> 3;
                size_t off = bbase + (size_t)((j >> 2) + L) * 2048
                           + (size_t)L * 32 + (j & 3) * 8 + (ib & 7);
                *(uint2*)(Dskew + off) = make_uint2(pack_bf16(d0, d1), pack_bf16(d2, d3));
            } else {
                const int jr  = 511 - j;
                const int irb = 508 - ib;             // i_r of i = ib+3 (ascending base)
                const int Lr  = irb >> 3;
                size_t off = bbase + HALF_E + (size_t)((jr >> 2) + Lr) * 2048
                           + (size_t)Lr * 32 + (jr & 3) * 8 + (irb & 7);
                *(uint2*)(Dskew + off) = make_uint2(pack_bf16(d3, d2), pack_bf16(d1, d0));
            }
        }
    }
}

// ---------------------------------------------------------------------------
// Meet-in-the-middle DTW half, one wave per block, 4-deep slab prefetch.
// grid = (half, batch). half 0: F(i,255); half 1: B(i,256) stored at index i.
template <bool HEAD>
__device__ __forceinline__ void dtw_step(int s, int lane,
    const uint4* __restrict__ base, uint4 (&q)[4],
    float (&V)[8], float (&top)[4], float& diag0)
{
    // unpack 32 bf16 -> f32 (off critical path)
    float d[4][8];
    #pragma unroll
    for (int c = 0; c < 4; ++c) {
        d[c][0] = __uint_as_float(q[c].x << 16);
        d[c][1] = __uint_as_float(q[c].x & 0xFFFF0000u);
        d[c][2] = __uint_as_float(q[c].y << 16);
        d[c][3] = __uint_as_float(q[c].y & 0xFFFF0000u);
        d[c][4] = __uint_as_float(q[c].z << 16);
        d[c][5] = __uint_as_float(q[c].z & 0xFFFF0000u);
        d[c][6] = __uint_as_float(q[c].w << 16);
        d[c][7] = __uint_as_float(q[c].w & 0xFFFF0000u);
    }
    // prefetch slab s+4 into q (4-deep pipeline)
    int sp = s + 4; if (sp > HSLAB - 1) sp = HSLAB - 1;
    const uint4* pp = base + (size_t)sp * SLAB_U4;
    q[0] = pp[0]; q[1] = pp[1]; q[2] = pp[2]; q[3] = pp[3];

    float sv0 = V[7], sv1 = V[7], sv2 = V[7], sv3 = V[7];

    const bool act = HEAD ? (s >= lane) : (s - lane <= 63);

    if (act) {
        float dg0 = diag0;
        if (HEAD) {
            if (s == lane) dg0 = (lane == 0) ? 0.0f : BIGF;  // chunk 0; corner starts at 0
        }
        float n[8][4];
        #pragma unroll
        for (int t = 0; t < 11; ++t) {
            #pragma unroll
            for (int c = 0; c < 4; ++c) {
                const int r = t - c;
                if (r >= 0 && r < 8) {
                    float A  = (r == 0) ? top[c] : n[r-1][c];
                    float Bv = (c == 0) ? V[r]   : n[r][c-1];
                    float Cv = (r == 0) ? ((c == 0) ? dg0    : top[c-1])
                                        : ((c == 0) ? V[r-1] : n[r-1][c-1]);
                    n[r][c] = d[c][r] + fminf(fminf(A, Bv), Cv);
                }
            }
        }
        #pragma unroll
        for (int r = 0; r < 8; ++r) V[r] = n[r][3];
        sv0 = n[7][0]; sv1 = n[7][1]; sv2 = n[7][2]; sv3 = n[7][3];
    }

    // boundary exchange (all lanes execute); save pre-update top[3] as diag
    diag0 = top[3];
    float t0 = __shfl_up(sv0, 1);
    float t1 = __shfl_up(sv1, 1);
    float t2 = __shfl_up(sv2, 1);
    float t3 = __shfl_up(sv3, 1);
    const bool l0 = (lane == 0);
    top[0] = l0 ? BIGF : t0;
    top[1] = l0 ? BIGF : t1;
    top[2] = l0 ? BIGF : t2;
    top[3] = l0 ? BIGF : t3;
}

__global__ void __launch_bounds__(64) dtw_kernel(const ushort* __restrict__ Dskew,
                                                 float* __restrict__ bound) {
    const int lane = threadIdx.x;
    const int h    = blockIdx.x;          // 0 = forward, 1 = reverse
    const int b    = blockIdx.y;
    const uint4* base = (const uint4*)(Dskew + ((size_t)b * 2 + h) * HALF_E) + lane * 4;

    float V[8];
    #pragma unroll
    for (int r = 0; r < 8; ++r) V[r] = BIGF;
    float top[4] = {BIGF, BIGF, BIGF, BIGF};
    float diag0  = BIGF;

    uint4 qA[4], qB[4], qC[4], qD[4];
    { const uint4* p = base;               qA[0]=p[0]; qA[1]=p[1]; qA[2]=p[2]; qA[3]=p[3]; }
    { const uint4* p = base + 1*SLAB_U4;   qB[0]=p[0]; qB[1]=p[1]; qB[2]=p[2]; qB[3]=p[3]; }
    { const uint4* p = base + 2*SLAB_U4;   qC[0]=p[0]; qC[1]=p[1]; qC[2]=p[2]; qC[3]=p[3]; }
    { const uint4* p = base + 3*SLAB_U4;   qD[0]=p[0]; qD[1]=p[1]; qD[2]=p[2]; qD[3]=p[3]; }

    for (int s = 0; s < 64; s += 4) {      // head: t>=0 guard + t==0 corner
        dtw_step<true>(s + 0, lane, base, qA, V, top, diag0);
        dtw_step<true>(s + 1, lane, base, qB, V, top, diag0);
        dtw_step<true>(s + 2, lane, base, qC, V, top, diag0);
        dtw_step<true>(s + 3, lane, base, qD, V, top, diag0);
    }
    for (int s = 64; s < 128; s += 4) {    // tail: t<=63 guard (s=127 = pad step)
        dtw_step<false>(s + 0, lane, base, qA, V, top, diag0);
        dtw_step<false>(s + 1, lane, base, qB, V, top, diag0);
        dtw_step<false>(s + 2, lane, base, qC, V, top, diag0);
        dtw_step<false>(s + 3, lane, base, qD, V, top, diag0);
    }

    // write boundary: h=0 -> F(8L+r, 255) at [8L+r]; h=1 -> B(i,256) at [i],
    // where V[r] corresponds to original row i = 511-(8L+r).
    float* out = bound + ((size_t)b * 2 + h) * 512;
    if (h == 0) {
        *(float4*)(out + 8 * lane)     = make_float4(V[0], V[1], V[2], V[3]);
        *(float4*)(out + 8 * lane + 4) = make_float4(V[4], V[5], V[6], V[7]);
    } else {
        const int ibase = 504 - 8 * lane;
        *(float4*)(out + ibase)     = make_float4(V[7], V[6], V[5], V[4]);
        *(float4*)(out + ibase + 4) = make_float4(V[3], V[2], V[1], V[0]);
    }
}

// ---------------------------------------------------------------------------
// Fused combine + finalize: ans_b = min_i F[i] + min(B[i], B[i+1]);
// out = mean_b ans_b. 1 block x 1024 threads; 32 threads per batch.
__global__ void __launch_bounds__(1024) combine_kernel(const float* __restrict__ bound,
                                                       float* __restrict__ out) {
    const int tid = threadIdx.x;
    const int b   = tid >> 5;             // 0..31
    const int li  = tid & 31;             // 0..31, 16 i's each
    const float* Fb = bound + (size_t)b * 1024;
    const float* Bb = Fb + 512;

    float mv = BIGF;
    #pragma unroll
    for (int k = 0; k < 16; ++k) {
        const int i = li * 16 + k;
        const float bn = (i == 511) ? Bb[511] : fminf(Bb[i], Bb[i + 1]);
        mv = fminf(mv, Fb[i] + bn);
    }
    #pragma unroll
    for (int o = 16; o > 0; o >>= 1) mv = fminf(mv, __shfl_xor(mv, o));

    __shared__ float bmin[32];
    if (li == 0) bmin[b] = mv;
    __syncthreads();
    if (tid < 32) {
        float v = bmin[tid];
        #pragma unroll
        for (int o = 16; o > 0; o >>= 1) v += __shfl_xor(v, o);
        if (tid == 0) out[0] = v * (1.0f / B_SZ);
    }
}

// ---------------------------------------------------------------------------
extern "C" void kernel_launch(void* const* d_in, const int* in_sizes, int n_in,
                              void* d_out, int out_size, void* d_ws, size_t ws_size,
                              hipStream_t stream) {
    const float* x  = (const float*)d_in[0];   // (32,512,256)
    const float* te = (const float*)d_in[1];   // (32,512,1024)
    float* out = (float*)d_out;

    char* ws = (char*)d_ws;
    ushort* Dskew = (ushort*)(ws);                                   // 33.6MB
    ushort* ybf   = (ushort*)(ws + (size_t)B_SZ * 2 * HALF_E * 2);   // 8.4MB
    ushort* xbf   = ybf + (size_t)B_SZ * M_SZ * D_SZ;                // 8.4MB
    float*  x2    = (float*)(xbf + (size_t)B_SZ * N_SZ * D_SZ);
    float*  y2    = x2 + B_SZ * N_SZ;
    float*  bound = y2 + B_SZ * M_SZ;                                // 32*2*512 f32

    pre_kernel<<<16384 + 4096, 256, 0, stream>>>(te, x, ybf, xbf, y2, x2);
    gemm_kernel<<<dim3(N_SZ/128, M_SZ/128, B_SZ), 256, 0, stream>>>(xbf, ybf, x2, y2, Dskew);
    dtw_kernel<<<dim3(2, B_SZ), 64, 0, stream>>>(Dskew, bound);
    combine_kernel<<<1, 1024, 0, stream>>>(bound, out);
}